// Round 2
// baseline (626.062 us; speedup 1.0000x reference)
//
#include <hip/hip_runtime.h>

// Problem constants (fixed instance)
constexpr int N_NODES = 32;
constexpr int D = 96;
constexpr int E_EDGES = 256;

// ws layout (floats)
// F[c][node][o][i]: 4*32*4*47 = 24064
// preds[1024][256] = 262144
// rbc[32]
constexpr int F_ELEMS = 4 * 32 * 4 * 47;

__device__ __forceinline__ int rfl(int x) { return __builtin_amdgcn_readfirstlane(x); }

// ---------------- Kernel 0: per-node conv1 feature tables ----------------
// F[c][node][o][i] = sum_k w1[o][c][k] * emb[node][2i+k]
__global__ void precompute_F(const float* __restrict__ emb, const float* __restrict__ w1,
                             float* __restrict__ F) {
    int idx = blockIdx.x * blockDim.x + threadIdx.x;  // 24064 total, grid exact
    int i = idx % 47;
    int o = (idx / 47) % 4;
    int node = (idx / (47 * 4)) % 32;
    int c = idx / (47 * 4 * 32);
    float acc = 0.f;
#pragma unroll
    for (int k = 0; k < 3; k++) acc += w1[(o * 4 + c) * 3 + k] * emb[node * D + 2 * i + k];
    F[idx] = acc;
}

// ---------------- Kernel 1: the 254k-sample CNN+MLP ----------------
// grid = 4096 blocks: block b -> pair p = b>>2, edge chunk e0 = (b&3)*64
// 256 threads: conv phase thread=(sample=tid>>2, ch=tid&3); fc phase (wave=tid>>6, lane=sample)
__global__ __launch_bounds__(256, 3)
void mlp_kernel(const float* __restrict__ F, const int* __restrict__ edges,
                const float* __restrict__ b1v,
                const float* __restrict__ w2, const float* __restrict__ b2,
                const float* __restrict__ w3, const float* __restrict__ b3,
                const float* __restrict__ fc1_w, const float* __restrict__ fc1_b,
                const float* __restrict__ fc2_w, const float* __restrict__ fc2_b,
                const float* __restrict__ fc3_w, const float* __restrict__ fc3_b,
                const float* __restrict__ fc4_w, const float* __restrict__ fc4_b,
                float* __restrict__ preds) {
    // LDS: conv region (aliased with a1t) + flat_t + h2c + part
    // h1t: [i<23][c<4][sample<64] = 5888 ; h2t: [i<10][c<4][sample<64] = 2560 -> 8448
    // a1t: [k<128][sample<64] = 8192 (alias of conv region)
    __shared__ float smem[8448 + 1024 + 2048 + 256];
    float* h1t = smem;
    float* h2t = smem + 5888;
    float* a1t = smem;  // alias, live after conv phase done
    float* flat_t = smem + 8448;           // [f<16][sample<64]
    float* h2c = smem + 8448 + 1024;       // [j<32][sample<64]
    float* part = smem + 8448 + 1024 + 2048;  // [wave<4][sample<64]

    const int tid = threadIdx.x;
    const int p = blockIdx.x >> 2;
    const int e0 = (blockIdx.x & 3) * 64;
    const int s = p >> 5, t = p & 31;
    if (s == t) return;  // contributes exactly 0 to rbc

    // ---- conv1 (table sum) + pool ----
    {
        const int sample = tid >> 2, o = tid & 3;
        const int e = e0 + sample;
        const int u = edges[2 * e], v = edges[2 * e + 1];
        const float* F0 = F + ((0 * 32 + s) * 4 + o) * 47;
        const float* F1 = F + ((1 * 32 + t) * 4 + o) * 47;
        const float* F2 = F + ((2 * 32 + u) * 4 + o) * 47;
        const float* F3 = F + ((3 * 32 + v) * 4 + o) * 47;
        const float bb = b1v[o];
        float pre[46];
#pragma unroll
        for (int i = 0; i < 46; i++) {  // element 46 is dropped by the pool
            float x = F0[i] + F1[i] + F2[i] + F3[i] + bb;
            pre[i] = fmaxf(x, 0.f);
        }
#pragma unroll
        for (int j = 0; j < 23; j++)
            h1t[(j * 4 + o) * 64 + sample] = fmaxf(pre[2 * j], pre[2 * j + 1]);
    }
    __syncthreads();
    // ---- conv2 + pool ----
    {
        const int sample = tid >> 2, o = tid & 3;
        float wreg[12];
#pragma unroll
        for (int q = 0; q < 12; q++) wreg[q] = w2[o * 12 + q];
        const float bb = b2[o];
        float pre[20];
#pragma unroll
        for (int i = 0; i < 20; i++) {  // element 20 dropped by pool
            float acc = bb;
#pragma unroll
            for (int c = 0; c < 4; c++)
#pragma unroll
                for (int k = 0; k < 3; k++)
                    acc = fmaf(wreg[c * 3 + k], h1t[((i + k) * 4 + c) * 64 + sample], acc);
            pre[i] = fmaxf(acc, 0.f);
        }
#pragma unroll
        for (int j = 0; j < 10; j++)
            h2t[(j * 4 + o) * 64 + sample] = fmaxf(pre[2 * j], pre[2 * j + 1]);
    }
    __syncthreads();
    // ---- conv3 + pool + flatten ----
    {
        const int sample = tid >> 2, o = tid & 3;
        float wreg[12];
#pragma unroll
        for (int q = 0; q < 12; q++) wreg[q] = w3[o * 12 + q];
        const float bb = b3[o];
        float pre[8];
#pragma unroll
        for (int i = 0; i < 8; i++) {
            float acc = bb;
#pragma unroll
            for (int c = 0; c < 4; c++)
#pragma unroll
                for (int k = 0; k < 3; k++)
                    acc = fmaf(wreg[c * 3 + k], h2t[((i + k) * 4 + c) * 64 + sample], acc);
            pre[i] = fmaxf(acc, 0.f);
        }
#pragma unroll
        for (int l = 0; l < 4; l++)
            flat_t[(o * 4 + l) * 64 + sample] = fmaxf(pre[2 * l], pre[2 * l + 1]);
    }
    __syncthreads();
    // ---- fc1: 16 -> 128, wave owns 32 j's, lane=sample ----
    {
        const int lane = tid & 63, wave = tid >> 6;
        const int j0 = rfl(wave * 32);
        float acc[32];
        const float* bp = fc1_b + j0;
#pragma unroll
        for (int jj = 0; jj < 32; jj++) acc[jj] = bp[jj];
#pragma unroll
        for (int kk = 0; kk < 16; kk++) {
            float a = flat_t[kk * 64 + lane];
            const float* wr = fc1_w + kk * 128 + j0;
#pragma unroll
            for (int jj = 0; jj < 32; jj++) acc[jj] = fmaf(a, wr[jj], acc[jj]);
        }
#pragma unroll
        for (int jj = 0; jj < 32; jj++)
            a1t[(j0 + jj) * 64 + lane] = fmaxf(acc[jj], 0.f);
    }
    __syncthreads();
    // ---- fc2 (128->256) fused with fc3 (256->128) in 32-wide chunks ----
    {
        const int lane = tid & 63, wave = tid >> 6;
        const int i0 = rfl(wave * 32);
        float acc3[32];
        const float* b3p = fc3_b + i0;
#pragma unroll
        for (int ii = 0; ii < 32; ii++) acc3[ii] = b3p[ii];
        for (int chunk = 0; chunk < 8; chunk++) {
            const int jw = rfl(chunk * 32 + wave * 8);
            float acc2[8];
            const float* b2p = fc2_b + jw;
#pragma unroll
            for (int jj = 0; jj < 8; jj++) acc2[jj] = b2p[jj];
#pragma unroll 4
            for (int k = 0; k < 128; k++) {
                float a = a1t[k * 64 + lane];
                const float* wr = fc2_w + k * 256 + jw;
#pragma unroll
                for (int jj = 0; jj < 8; jj++) acc2[jj] = fmaf(a, wr[jj], acc2[jj]);
            }
#pragma unroll
            for (int jj = 0; jj < 8; jj++)
                h2c[(wave * 8 + jj) * 64 + lane] = fmaxf(acc2[jj], 0.f);
            __syncthreads();
            const int J0 = rfl(chunk * 32);
#pragma unroll 4
            for (int jj = 0; jj < 32; jj++) {
                float a = h2c[jj * 64 + lane];
                const float* wr = fc3_w + (J0 + jj) * 128 + i0;
#pragma unroll
                for (int ii = 0; ii < 32; ii++) acc3[ii] = fmaf(a, wr[ii], acc3[ii]);
            }
            __syncthreads();
        }
        // ---- fc4 partial dot over this wave's 32 i's ----
        float partial = 0.f;
        const float* w4 = fc4_w + i0;
#pragma unroll
        for (int ii = 0; ii < 32; ii++) partial += fmaxf(acc3[ii], 0.f) * w4[ii];
        part[wave * 64 + lane] = partial;
    }
    __syncthreads();
    if (tid < 64) {
        float pred = part[tid] + part[64 + tid] + part[128 + tid] + part[192 + tid] + fc4_b[0];
        preds[p * 256 + e0 + tid] = pred;
    }
}

// ---------------- Kernel 2: 3-step propagation ----------------
__global__ void prop_kernel(const int* __restrict__ edges,
                            const float* __restrict__ preds,
                            float* __restrict__ rbc) {
    const int p = blockIdx.x;
    const int s = p >> 5, t = p & 31;
    if (s == t) return;
    __shared__ float x[32], xn[32], racc[32];
    const int tid = threadIdx.x;
    if (tid < 32) { x[tid] = (tid == s) ? 1.f : 0.f; racc[tid] = 0.f; }
    const int u = edges[2 * tid], v = edges[2 * tid + 1];
    const float pr = preds[p * 256 + tid];
    for (int step = 0; step < 3; step++) {
        if (tid < 32) xn[tid] = 0.f;
        __syncthreads();
        atomicAdd(&xn[v], x[u] * pr);
        __syncthreads();
        if (tid < 32) { racc[tid] += xn[tid]; x[tid] = xn[tid]; }
        __syncthreads();
    }
    if (tid < 32) atomicAdd(&rbc[tid], racc[tid]);
}

// ---------------- Kernel 3: normalize ----------------
__global__ void norm_kernel(const float* __restrict__ rbc, float* __restrict__ out) {
    int tid = threadIdx.x;
    if (tid < 32) {
        float ssum = 0.f;
#pragma unroll
        for (int j = 0; j < 32; j++) ssum += rbc[j];
        out[tid] = rbc[tid] / ssum;
    }
}

extern "C" void kernel_launch(void* const* d_in, const int* in_sizes, int n_in,
                              void* d_out, int out_size, void* d_ws, size_t ws_size,
                              hipStream_t stream) {
    const float* emb = (const float*)d_in[0];
    const int* edges = (const int*)d_in[1];
    const float* w1 = (const float*)d_in[2];
    const float* b1 = (const float*)d_in[3];
    const float* w2 = (const float*)d_in[4];
    const float* b2 = (const float*)d_in[5];
    const float* w3 = (const float*)d_in[6];
    const float* b3 = (const float*)d_in[7];
    const float* fc1_w = (const float*)d_in[8];
    const float* fc1_b = (const float*)d_in[9];
    const float* fc2_w = (const float*)d_in[10];
    const float* fc2_b = (const float*)d_in[11];
    const float* fc3_w = (const float*)d_in[12];
    const float* fc3_b = (const float*)d_in[13];
    const float* fc4_w = (const float*)d_in[14];
    const float* fc4_b = (const float*)d_in[15];

    float* ws = (float*)d_ws;
    float* F = ws;                       // 24064 floats
    float* preds = ws + F_ELEMS;         // 262144 floats
    float* rbc = ws + F_ELEMS + 1024 * 256;  // 32 floats
    float* out = (float*)d_out;

    precompute_F<<<dim3(94), dim3(256), 0, stream>>>(emb, w1, F);
    mlp_kernel<<<dim3(4096), dim3(256), 0, stream>>>(
        F, edges, b1, w2, b2, w3, b3, fc1_w, fc1_b, fc2_w, fc2_b, fc3_w, fc3_b,
        fc4_w, fc4_b, preds);
    (void)hipMemsetAsync(rbc, 0, 32 * sizeof(float), stream);
    prop_kernel<<<dim3(1024), dim3(256), 0, stream>>>(edges, preds, rbc);
    norm_kernel<<<dim3(1), dim3(64), 0, stream>>>(rbc, out);
}